// Round 1
// baseline (340.126 us; speedup 1.0000x reference)
//
#include <hip/hip_runtime.h>
#include <math.h>

// GRU cell, per-position weights. B=16,N=207,C=64,H=64 -> 3312 positions.
// v3: latency-bound fix. Warm-L3 dispatches ran at the same 120us as cold ones
// (rocprof: FETCH 0.8MB vs 161MB, identical dur) -> not BW-bound; occupancy 47%
// capped by 16KB Wch LDS staging. Reorder phases so r is computed first, then
// the candidate term accumulates directly against rh while streaming Wh's
// z+c columns: no Wch staging, no divergent stream loop, no serial LDS tail.
// LDS 20.5KB -> ~5.3KB; 256 thr/block, target 8 blocks/CU (32 waves, 100%).

#define GC 64    // input channels
#define GH 64    // hidden
#define J3 192   // 3*H
#define WPP (GC * J3)   // floats per weight matrix per position

__global__ __launch_bounds__(256, 8) void gru_cell_v3(
    const float* __restrict__ x,      // (P, 64)
    const float* __restrict__ state,  // (P, 64)
    const float* __restrict__ Wx,     // (P, 64, 192)
    const float* __restrict__ Wh,     // (P, 64, 192)
    const float* __restrict__ b,      // (P, 192)
    float* __restrict__ out)          // (P, 64)
{
    const int pos = blockIdx.x;
    const int t = threadIdx.x;        // 0..255

    __shared__ float x_s[GC];
    __shared__ float mult_s[2 * GH];  // [0,64): h ; [64,128): r*h
    __shared__ float part[1024];      // phase1: [16][64] ; phase2: [8][128]
    __shared__ float z_s[GH];

    if (t < GC)           x_s[t]          = x[(size_t)pos * GC + t];
    else if (t < GC + GH) mult_s[t - GC]  = state[(size_t)pos * GH + (t - GC)];
    __syncthreads();

    const float4* __restrict__ Wx4 = (const float4*)(Wx + (size_t)pos * WPP);
    const float4* __restrict__ Wh4 = (const float4*)(Wh + (size_t)pos * WPP);

    // ---- Phase 1: r-gate columns 0..63 of both matrices ----
    // thread -> (f4col jg 0..15, row-phase rp 0..15); rows c = rp + 16k.
    // Wave loads 4 x 256B segments per instr (rows rp..rp+3), fully used lines.
    {
        const int jg = t & 15;
        const int rp = t >> 4;
        float4 acc = {0.f, 0.f, 0.f, 0.f};
        #pragma unroll
        for (int k = 0; k < 4; ++k) {
            const int c = rp + 16 * k;
            const float4 wx4 = Wx4[c * 48 + jg];
            const float4 wh4 = Wh4[c * 48 + jg];
            const float xs = x_s[c];
            const float hs = mult_s[c];
            acc.x += xs * wx4.x + hs * wh4.x;
            acc.y += xs * wx4.y + hs * wh4.y;
            acc.z += xs * wx4.z + hs * wh4.z;
            acc.w += xs * wx4.w + hs * wh4.w;
        }
        *((float4*)&part[rp * 64 + 4 * jg]) = acc;  // contiguous f4, conflict-free
    }
    __syncthreads();

    // Reduce 16 row-phases; compute r and rh = r*h.
    if (t < GH) {
        float v = b[(size_t)pos * J3 + t];
        #pragma unroll
        for (int rp = 0; rp < 16; ++rp) v += part[rp * 64 + t];
        const float r = 1.f / (1.f + expf(-v));
        mult_s[GH + t] = r * mult_s[t];
    }
    __syncthreads();

    // ---- Phase 2: z columns (64..127, mult = h) and candidate (128..191,
    // mult = rh) of both matrices. Multiplier picked by computed LDS address:
    // zero divergence. thread -> (f4col jg 0..31, row-phase rp 0..7).
    float vc = 0.f;
    {
        const int jg = t & 31;
        const int rp = t >> 5;
        const int msel = (jg & 16) << 2;   // 0 -> h, 64 -> rh
        float4 acc = {0.f, 0.f, 0.f, 0.f};
        #pragma unroll 4
        for (int k = 0; k < 8; ++k) {
            const int c = rp + 8 * k;
            const float4 wx4 = Wx4[c * 48 + 16 + jg];
            const float4 wh4 = Wh4[c * 48 + 16 + jg];
            const float xs = x_s[c];
            const float ms = mult_s[msel + c];
            acc.x += xs * wx4.x + ms * wh4.x;
            acc.y += xs * wx4.y + ms * wh4.y;
            acc.z += xs * wx4.z + ms * wh4.z;
            acc.w += xs * wx4.w + ms * wh4.w;
        }
        *((float4*)&part[rp * 128 + 4 * jg]) = acc;
    }
    __syncthreads();

    // Reduce 8 row-phases. t<64 owns z column t; t in [64,128) owns candidate.
    if (t < 2 * GH) {
        float v = b[(size_t)pos * J3 + GH + t];
        #pragma unroll
        for (int rp = 0; rp < 8; ++rp) v += part[rp * 128 + t];
        if (t < GH) z_s[t] = 1.f / (1.f + expf(-v));
        else        vc = v;
    }
    __syncthreads();

    if (t >= GH && t < 2 * GH) {
        const int j = t - GH;
        const float hc = tanhf(vc);
        const float z = z_s[j];
        out[(size_t)pos * GH + j] = (1.f - z) * mult_s[j] + z * hc;
    }
}

extern "C" void kernel_launch(void* const* d_in, const int* in_sizes, int n_in,
                              void* d_out, int out_size, void* d_ws, size_t ws_size,
                              hipStream_t stream) {
    const float* x     = (const float*)d_in[0];
    const float* state = (const float*)d_in[1];
    const float* Wx    = (const float*)d_in[2];
    const float* Wh    = (const float*)d_in[3];
    const float* b     = (const float*)d_in[4];
    float* out = (float*)d_out;

    const int npos = in_sizes[0] / GC;   // B*N = 3312

    gru_cell_v3<<<npos, 256, 0, stream>>>(x, state, Wx, Wh, b, out);
}

// Round 2
// 331.799 us; speedup vs baseline: 1.0251x; 1.0251x over previous
//
#include <hip/hip_runtime.h>
#include <math.h>

// GRU cell, per-position weights. B=16,N=207,C=64,H=64 -> 3312 positions.
// v4: max memory-level parallelism. v2 (47% occ) and v3 (75% occ) both sat at
// 119-121us / 2.75 TB/s, warm-L3 identical to cold -> not BW/occupancy/L3
// bound. VGPR=28 showed the compiler serialized loads into a ~3-deep window,
// and the phase structure idles the vmem pipe during reduces/barriers.
// v4 issues ALL 26 global loads (x, h, b, 24x float4 weights) back-to-back
// before any barrier: phase-2 weight LOADS don't depend on r, only their FMAs
// do. x/h broadcast via in-wave __shfl (wave-redundant 256B loads) so the
// first __syncthreads comes after phase-1 FMAs. ~96 data VGPRs ->
// __launch_bounds__(256,4) (<=128 VGPR, 4 blocks/CU, 16 waves).

#define GC 64    // input channels
#define GH 64    // hidden
#define J3 192   // 3*H
#define WPP (GC * J3)   // floats per weight matrix per position

__global__ __launch_bounds__(256, 4) void gru_cell_v4(
    const float* __restrict__ x,      // (P, 64)
    const float* __restrict__ state,  // (P, 64)
    const float* __restrict__ Wx,     // (P, 64, 192)
    const float* __restrict__ Wh,     // (P, 64, 192)
    const float* __restrict__ b,      // (P, 192)
    float* __restrict__ out)          // (P, 64)
{
    const int pos = blockIdx.x;
    const int t = threadIdx.x;        // 0..255
    const int lane = t & 63;

    __shared__ float mult_s[2 * GH];  // [0,64): h ; [64,128): r*h
    __shared__ float part[1024];      // phase1: [16][64] ; phase2: [8][128]
    __shared__ float z_s[GH];

    // ---- Issue EVERY global load up front; nothing blocks their issue ----
    const float xv = x[(size_t)pos * GC + lane];       // wave-redundant bcast copy
    const float hv = state[(size_t)pos * GH + lane];
    float bv1 = 0.f, bv2 = 0.f;
    if (t < GH)     bv1 = b[(size_t)pos * J3 + t];
    if (t < 2 * GH) bv2 = b[(size_t)pos * J3 + GH + t];

    const float4* __restrict__ Wx4 = (const float4*)(Wx + (size_t)pos * WPP);
    const float4* __restrict__ Wh4 = (const float4*)(Wh + (size_t)pos * WPP);

    const int jg1 = t & 15, rp1 = t >> 4;   // phase-1 mapping (16 row phases)
    const int jg2 = t & 31, rp2 = t >> 5;   // phase-2 mapping (8 row phases)

    float4 wx1[4], wh1[4];    // r-gate columns 0..63
    float4 wx2[8], wh2[8];    // z + candidate columns 64..191
    #pragma unroll
    for (int k = 0; k < 4; ++k) {
        const int c = rp1 + 16 * k;
        wx1[k] = Wx4[c * 48 + jg1];
        wh1[k] = Wh4[c * 48 + jg1];
    }
    #pragma unroll
    for (int k = 0; k < 8; ++k) {
        const int c = rp2 + 8 * k;
        wx2[k] = Wx4[c * 48 + 16 + jg2];
        wh2[k] = Wh4[c * 48 + 16 + jg2];
    }

    // ---- Phase 1 FMAs (r-gate), x/h via in-wave shuffle: no barrier yet ----
    {
        float4 acc = {0.f, 0.f, 0.f, 0.f};
        #pragma unroll
        for (int k = 0; k < 4; ++k) {
            const int c = rp1 + 16 * k;
            const float xs = __shfl(xv, c);
            const float hs = __shfl(hv, c);
            acc.x += xs * wx1[k].x + hs * wh1[k].x;
            acc.y += xs * wx1[k].y + hs * wh1[k].y;
            acc.z += xs * wx1[k].z + hs * wh1[k].z;
            acc.w += xs * wx1[k].w + hs * wh1[k].w;
        }
        *((float4*)&part[rp1 * 64 + 4 * jg1]) = acc;
    }
    __syncthreads();

    // Reduce 16 row phases; r, then publish h and r*h for phase 2.
    if (t < GH) {
        float v = bv1;
        #pragma unroll
        for (int rp = 0; rp < 16; ++rp) v += part[rp * 64 + t];
        const float r = 1.f / (1.f + expf(-v));
        mult_s[t]      = hv;            // lane t of wave 0 holds h[t]
        mult_s[GH + t] = r * hv;
    }
    __syncthreads();

    // ---- Phase 2 FMAs from registers (weights landed long ago) ----
    {
        const int msel = (jg2 & 16) << 2;    // 0 -> h, 64 -> r*h
        float4 acc = {0.f, 0.f, 0.f, 0.f};
        #pragma unroll
        for (int k = 0; k < 8; ++k) {
            const int c = rp2 + 8 * k;
            const float xs = __shfl(xv, c);
            const float ms = mult_s[msel + c];
            acc.x += xs * wx2[k].x + ms * wh2[k].x;
            acc.y += xs * wx2[k].y + ms * wh2[k].y;
            acc.z += xs * wx2[k].z + ms * wh2[k].z;
            acc.w += xs * wx2[k].w + ms * wh2[k].w;
        }
        *((float4*)&part[rp2 * 128 + 4 * jg2]) = acc;
    }
    __syncthreads();

    // Reduce 8 row phases. t<64 -> z column t; t in [64,128) -> candidate.
    float vc = 0.f;
    if (t < 2 * GH) {
        float v = bv2;
        #pragma unroll
        for (int rp = 0; rp < 8; ++rp) v += part[rp * 128 + t];
        if (t < GH) z_s[t] = 1.f / (1.f + expf(-v));
        else        vc = v;
    }
    __syncthreads();

    if (t >= GH && t < 2 * GH) {
        const int j = t - GH;
        const float hc = tanhf(vc);
        const float z = z_s[j];
        out[(size_t)pos * GH + j] = (1.f - z) * mult_s[j] + z * hc;
    }
}

extern "C" void kernel_launch(void* const* d_in, const int* in_sizes, int n_in,
                              void* d_out, int out_size, void* d_ws, size_t ws_size,
                              hipStream_t stream) {
    const float* x     = (const float*)d_in[0];
    const float* state = (const float*)d_in[1];
    const float* Wx    = (const float*)d_in[2];
    const float* Wh    = (const float*)d_in[3];
    const float* b     = (const float*)d_in[4];
    float* out = (float*)d_out;

    const int npos = in_sizes[0] / GC;   // B*N = 3312

    gru_cell_v4<<<npos, 256, 0, stream>>>(x, state, Wx, Wh, b, out);
}